// Round 4
// baseline (296.252 us; speedup 1.0000x reference)
//
#include <hip/hip_runtime.h>
#include <hip/hip_bf16.h>
#include <stdint.h>

typedef unsigned short u16;
typedef __bf16 bf16x8 __attribute__((ext_vector_type(8)));
typedef float f32x4 __attribute__((ext_vector_type(4)));
typedef unsigned short u16x8 __attribute__((ext_vector_type(8)));

#define QEPS 1e-8f

__device__ __forceinline__ u16 f32_to_bf16_rne(float f) {
    uint32_t u = __float_as_uint(f);
    u += 0x7fffu + ((u >> 16) & 1u);
    return (u16)(u >> 16);
}

// ---------------- x: f32 -> bf16, [M][K] row-major ----------------
__global__ void cvt_x_bf16(const float* __restrict__ x, u16* __restrict__ xb, int n8) {
    int idx = blockIdx.x * blockDim.x + threadIdx.x;
    if (idx >= n8) return;
    const float4* p = (const float4*)(x + (size_t)idx * 8);
    float4 a = p[0], b = p[1];
    u16x8 r;
    r[0] = f32_to_bf16_rne(a.x); r[1] = f32_to_bf16_rne(a.y);
    r[2] = f32_to_bf16_rne(a.z); r[3] = f32_to_bf16_rne(a.w);
    r[4] = f32_to_bf16_rne(b.x); r[5] = f32_to_bf16_rne(b.y);
    r[6] = f32_to_bf16_rne(b.z); r[7] = f32_to_bf16_rne(b.w);
    *(u16x8*)(xb + (size_t)idx * 8) = r;
}

// ------- weight dequant: w_dq[n][k] = round(w/s)*s, bf16, [N][K] -------
__global__ void dequant_w_bf16(const float* __restrict__ w, const float* __restrict__ ss,
                               u16* __restrict__ wb, int N, int K) {
    int idx = blockIdx.x * blockDim.x + threadIdx.x;
    int pr = K >> 3;
    if (idx >= N * pr) return;
    int n = idx / pr;
    int k8 = (idx - n * pr) << 3;
    float s = ss[(size_t)(k8 >> 7) * N + n] + QEPS;
    const float4* p = (const float4*)(w + (size_t)n * K + k8);
    float4 a = p[0], b = p[1];
    float v[8] = {a.x, a.y, a.z, a.w, b.x, b.y, b.z, b.w};
    u16x8 r;
#pragma unroll
    for (int i = 0; i < 8; ++i) {
        float q = rintf(v[i] / s);
        r[i] = f32_to_bf16_rne(q * s);
    }
    *(u16x8*)(wb + (size_t)n * K + k8) = r;
}

// ======================= 256x256 pipelined bf16 GEMM =======================
// Unit = 32-k slab. Ring of 4 units (128 KiB LDS), stage lookahead 3, counted
// vmcnt(6). 2 phases/unit; fragments prefetched ONE PHASE EARLY so every MFMA
// cluster's ds_reads were issued before the previous cluster ran.
#define BM 256
#define BN 256
#define SLOTB 32768     // bytes per ring slot: A 16K + B 16K
#define ABYT 16384
#define LDSB 131072

#define ASYNC16(g, l)                                                                      \
    __builtin_amdgcn_global_load_lds((const __attribute__((address_space(1))) void*)(g),   \
                                     (__attribute__((address_space(3))) void*)(l), 16, 0, 0)
#define VMCNT(n) asm volatile("s_waitcnt vmcnt(" #n ")" ::: "memory")
#define SBAR()   __builtin_amdgcn_sched_barrier(0)
#define BAR()    __builtin_amdgcn_s_barrier()

__global__ __launch_bounds__(512, 2) void gemm_bf16_bt_256(
        const u16* __restrict__ A,    // [M][K] bf16
        const u16* __restrict__ B,    // [N][K] bf16
        const float* __restrict__ bias,
        float* __restrict__ C,        // [M][N] f32
        int M, int N, int K) {
    extern __shared__ char lds[];
    const int tid  = threadIdx.x;
    const int wave = tid >> 6;
    const int lane = tid & 63;

    // XCD-aware bijective swizzle (grid 512, %8==0)
    const int nwg = gridDim.x;
    const int cpx = nwg >> 3;
    const int bid = blockIdx.x;
    const int swz = (bid & 7) * cpx + (bid >> 3);
    const int nbn = N / BN;
    const int bm  = swz / nbn;
    const int bn  = swz - bm * nbn;

    const int wr = wave >> 2;                // 0..1 -> 128 rows
    const int wc = wave & 3;                 // 0..3 -> 64 cols

    // staging sources (k pre-swizzled: kb ^= ((row>>1)&3)<<4, involution in 64-B row)
    const int srow  = tid >> 2;                                        // 0..127
    const int kbsrc = ((tid & 3) << 4) ^ (((tid >> 3) & 3) << 4);
    const char* gA0 = (const char*)A + ((size_t)(bm * BM + srow) * K) * 2 + kbsrc;
    const char* gA1 = (const char*)A + ((size_t)(bm * BM + 128 + srow) * K) * 2 + kbsrc;
    const char* gB0 = (const char*)B + ((size_t)(bn * BN + srow) * K) * 2 + kbsrc;
    const char* gB1 = (const char*)B + ((size_t)(bn * BN + 128 + srow) * K) * 2 + kbsrc;

    auto stageA = [&](int t) {
        const size_t ko = (size_t)t << 6;               // t * 32k * 2B per row
        char* d = lds + ((t & 3) * SLOTB) + (wave << 10);
        ASYNC16(gA0 + ko, d);
        ASYNC16(gA1 + ko, d + 8192);
    };
    auto stageB = [&](int t) {
        const size_t ko = (size_t)t << 6;
        char* d = lds + ((t & 3) * SLOTB) + ABYT + (wave << 10);
        ASYNC16(gB0 + ko, d);
        ASYNC16(gB1 + ko, d + 8192);
    };

    // fragment read bases (same XOR on read address)
    const int kx = ((lane >> 4) ^ ((lane >> 1) & 3)) << 4;
    const char* pa = lds + (size_t)(wr * 128 + (lane & 15)) * 64 + kx;
    const char* pb = lds + ABYT + (size_t)(wc * 64 + (lane & 15)) * 64 + kx;

    f32x4 acc[8][4] = {};
    bf16x8 rB[4], rA0[4], rA1[4], rB2[4], rA02[4];

#define MFMA16_LO()                                                           \
    _Pragma("unroll") for (int m = 0; m < 4; ++m)                             \
    _Pragma("unroll") for (int n = 0; n < 4; ++n)                             \
        acc[m][n] = __builtin_amdgcn_mfma_f32_16x16x32_bf16(rA0[m], rB[n], acc[m][n], 0, 0, 0);
#define MFMA16_HI()                                                           \
    _Pragma("unroll") for (int m = 0; m < 4; ++m)                             \
    _Pragma("unroll") for (int n = 0; n < 4; ++n)                             \
        acc[m + 4][n] = __builtin_amdgcn_mfma_f32_16x16x32_bf16(rA1[m], rB[n], acc[m + 4][n], 0, 0, 0);

#define UNIT_BODY(u, VMSTMT, DO_STAGE, DO_PREF)                               \
    {                                                                         \
        const int sb  = ((u) & 3) * SLOTB;                                    \
        const int sb1 = (((u) + 1) & 3) * SLOTB;                              \
        /* ph1: prefetch rA1 (consumed in ph2) */                             \
        _Pragma("unroll") for (int m = 0; m < 4; ++m)                         \
            rA1[m] = *(const bf16x8*)(pa + sb + (m + 4) * 1024);              \
        if (DO_STAGE) stageA((u) + 3);                                        \
        VMSTMT;                                                               \
        SBAR(); BAR(); SBAR();                                                \
        __builtin_amdgcn_s_setprio(1);                                        \
        MFMA16_LO();                                                          \
        __builtin_amdgcn_s_setprio(0);                                        \
        BAR();                                                                \
        /* ph2: prefetch rB', rA0' of unit u+1 (consumed next ph1) */         \
        if (DO_PREF) {                                                        \
            _Pragma("unroll") for (int n = 0; n < 4; ++n)                     \
                rB2[n] = *(const bf16x8*)(pb + sb1 + n * 1024);               \
            _Pragma("unroll") for (int m = 0; m < 4; ++m)                     \
                rA02[m] = *(const bf16x8*)(pa + sb1 + m * 1024);              \
        }                                                                     \
        if (DO_STAGE) stageB((u) + 3);                                        \
        SBAR(); BAR(); SBAR();                                                \
        __builtin_amdgcn_s_setprio(1);                                        \
        MFMA16_HI();                                                          \
        __builtin_amdgcn_s_setprio(0);                                        \
        BAR();                                                                \
        _Pragma("unroll") for (int i = 0; i < 4; ++i) { rB[i] = rB2[i]; rA0[i] = rA02[i]; } \
    }

    const int NU = K >> 5;                   // 128 units of 32 k

    // prologue: stage units 0,1,2 (12 loads); confirm unit 0; load its ph1 frags
    stageA(0); stageB(0); stageA(1); stageB(1); stageA(2); stageB(2);
    VMCNT(8);
    BAR();
#pragma unroll
    for (int n = 0; n < 4; ++n) rB[n] = *(const bf16x8*)(pb + n * 1024);
#pragma unroll
    for (int m = 0; m < 4; ++m) rA0[m] = *(const bf16x8*)(pa + m * 1024);

    for (int u = 0; u < NU - 3; ++u)
        UNIT_BODY(u, VMCNT(6), true, true);     // queue: u+1(4)+u+2(4)+u+3A(2)=10 -> confirm u+1
    UNIT_BODY(NU - 3, VMCNT(4), false, true);   // queue: u+1(4)+u+2(4)=8 -> confirm u+1
    UNIT_BODY(NU - 2, VMCNT(0), false, true);   // queue: u+1(4) -> confirm
    UNIT_BODY(NU - 1, (void)0, false, false);

    // ---- epilogue: C/D layout row=(lane>>4)*4+i, col=lane&15 ----
    const int r0 = bm * BM + wr * 128 + ((lane >> 4) << 2);
    const int c0 = bn * BN + wc * 64 + (lane & 15);
    float bv[4];
#pragma unroll
    for (int n = 0; n < 4; ++n) bv[n] = bias[c0 + n * 16];
#pragma unroll
    for (int m = 0; m < 8; ++m)
#pragma unroll
        for (int n = 0; n < 4; ++n)
#pragma unroll
            for (int i = 0; i < 4; ++i)
                C[(size_t)(r0 + m * 16 + i) * N + (c0 + n * 16)] = acc[m][n][i] + bv[n];
}

extern "C" void kernel_launch(void* const* d_in, const int* in_sizes, int n_in,
                              void* d_out, int out_size, void* d_ws, size_t ws_size,
                              hipStream_t stream) {
    const float* x    = (const float*)d_in[0];   // [B,S,K] f32
    const float* w    = (const float*)d_in[1];   // [N,K]   f32
    const float* bias = (const float*)d_in[2];   // [N]     f32
    const float* ss   = (const float*)d_in[3];   // [K/128, N] f32
    float* out        = (float*)d_out;           // [B,S,N] f32

    const int N = in_sizes[2];            // 4096
    const int K = in_sizes[1] / N;        // 4096
    const int M = in_sizes[0] / K;        // 8192

    u16* xb = (u16*)d_ws;                        // [M][K] bf16
    u16* wb = xb + (size_t)M * K;                // [N][K] bf16

    int n8x = (M * K) >> 3;
    cvt_x_bf16<<<(n8x + 255) / 256, 256, 0, stream>>>(x, xb, n8x);

    int n8w = (N * K) >> 3;
    dequant_w_bf16<<<(n8w + 255) / 256, 256, 0, stream>>>(w, ss, wb, N, K);

    (void)hipFuncSetAttribute((const void*)gemm_bf16_bt_256,
                              hipFuncAttributeMaxDynamicSharedMemorySize, LDSB);
    dim3 grid((M / BM) * (N / BN));              // 32*16 = 512, %8 == 0
    gemm_bf16_bt_256<<<grid, 512, LDSB, stream>>>(xb, wb, bias, out, M, N, K);
}

// Round 5
// 285.299 us; speedup vs baseline: 1.0384x; 1.0384x over previous
//
#include <hip/hip_runtime.h>
#include <hip/hip_bf16.h>
#include <stdint.h>

typedef unsigned short u16;
typedef __bf16 bf16x8 __attribute__((ext_vector_type(8)));
typedef float f32x4 __attribute__((ext_vector_type(4)));
typedef unsigned short u16x8 __attribute__((ext_vector_type(8)));

#define QEPS 1e-8f

__device__ __forceinline__ u16 f32_to_bf16_rne(float f) {
    uint32_t u = __float_as_uint(f);
    u += 0x7fffu + ((u >> 16) & 1u);
    return (u16)(u >> 16);
}

// ---------------- x: f32 -> bf16, [M][K] row-major ----------------
__global__ void cvt_x_bf16(const float* __restrict__ x, u16* __restrict__ xb, int n8) {
    int idx = blockIdx.x * blockDim.x + threadIdx.x;
    if (idx >= n8) return;
    const float4* p = (const float4*)(x + (size_t)idx * 8);
    float4 a = p[0], b = p[1];
    u16x8 r;
    r[0] = f32_to_bf16_rne(a.x); r[1] = f32_to_bf16_rne(a.y);
    r[2] = f32_to_bf16_rne(a.z); r[3] = f32_to_bf16_rne(a.w);
    r[4] = f32_to_bf16_rne(b.x); r[5] = f32_to_bf16_rne(b.y);
    r[6] = f32_to_bf16_rne(b.z); r[7] = f32_to_bf16_rne(b.w);
    *(u16x8*)(xb + (size_t)idx * 8) = r;
}

// ------- weight dequant: w_dq[n][k] = round(w/s)*s, bf16, [N][K] -------
__global__ void dequant_w_bf16(const float* __restrict__ w, const float* __restrict__ ss,
                               u16* __restrict__ wb, int N, int K) {
    int idx = blockIdx.x * blockDim.x + threadIdx.x;
    int pr = K >> 3;
    if (idx >= N * pr) return;
    int n = idx / pr;
    int k8 = (idx - n * pr) << 3;
    float s = ss[(size_t)(k8 >> 7) * N + n] + QEPS;
    const float4* p = (const float4*)(w + (size_t)n * K + k8);
    float4 a = p[0], b = p[1];
    float v[8] = {a.x, a.y, a.z, a.w, b.x, b.y, b.z, b.w};
    u16x8 r;
#pragma unroll
    for (int i = 0; i < 8; ++i) {
        float q = rintf(v[i] / s);
        r[i] = f32_to_bf16_rne(q * s);
    }
    *(u16x8*)(wb + (size_t)n * K + k8) = r;
}

// ======================= 256x256 pipelined bf16 GEMM =======================
// Ring of 4 x BK=32 slabs (128 KiB LDS), stage lookahead 3, counted vmcnt(8),
// ONE barrier per slab. The 12 ds_read_b128 of a slab are rotated INTO the
// 32-MFMA cluster; compiler counted-lgkm overlaps LDS pipe with MFMA pipe.
#define BM 256
#define BN 256
#define SLOTB 32768     // bytes per ring slot: A 16K + B 16K
#define ABYT 16384
#define LDSB 131072

#define ASYNC16(g, l)                                                                      \
    __builtin_amdgcn_global_load_lds((const __attribute__((address_space(1))) void*)(g),   \
                                     (__attribute__((address_space(3))) void*)(l), 16, 0, 0)
#define VMCNT(n) asm volatile("s_waitcnt vmcnt(" #n ")" ::: "memory")
#define BAR()    __builtin_amdgcn_s_barrier()
#define MFMA(a, b, c) __builtin_amdgcn_mfma_f32_16x16x32_bf16((a), (b), (c), 0, 0, 0)

__global__ __launch_bounds__(512, 2) void gemm_bf16_bt_256(
        const u16* __restrict__ A,    // [M][K] bf16
        const u16* __restrict__ B,    // [N][K] bf16
        const float* __restrict__ bias,
        float* __restrict__ C,        // [M][N] f32
        int M, int N, int K) {
    extern __shared__ char lds[];
    const int tid  = threadIdx.x;
    const int wave = tid >> 6;
    const int lane = tid & 63;

    // XCD-aware bijective swizzle (grid 512, %8==0)
    const int nwg = gridDim.x;
    const int cpx = nwg >> 3;
    const int bid = blockIdx.x;
    const int swz = (bid & 7) * cpx + (bid >> 3);
    const int nbn = N / BN;
    const int bm  = swz / nbn;
    const int bn  = swz - bm * nbn;

    const int wr = wave >> 2;                // 0..1 -> 128 rows
    const int wc = wave & 3;                 // 0..3 -> 64 cols

    // staging sources (k pre-swizzled: kb ^= ((row>>1)&3)<<4, involution in 64-B row)
    const int srow  = tid >> 2;                                        // 0..127
    const int kbsrc = ((tid & 3) << 4) ^ (((tid >> 3) & 3) << 4);
    const char* gA0 = (const char*)A + ((size_t)(bm * BM + srow) * K) * 2 + kbsrc;
    const char* gA1 = (const char*)A + ((size_t)(bm * BM + 128 + srow) * K) * 2 + kbsrc;
    const char* gB0 = (const char*)B + ((size_t)(bn * BN + srow) * K) * 2 + kbsrc;
    const char* gB1 = (const char*)B + ((size_t)(bn * BN + 128 + srow) * K) * 2 + kbsrc;

    auto STAGE = [&](int t) {
        const size_t ko = (size_t)t << 6;               // t * 32k * 2B
        char* d = lds + ((t & 3) * SLOTB) + (wave << 10);
        ASYNC16(gA0 + ko, d);
        ASYNC16(gA1 + ko, d + 8192);
        ASYNC16(gB0 + ko, d + ABYT);
        ASYNC16(gB1 + ko, d + ABYT + 8192);
    };

    // fragment read bases (same XOR on read address)
    const int kx = ((lane >> 4) ^ ((lane >> 1) & 3)) << 4;
    const char* pa = lds + (size_t)(wr * 128 + (lane & 15)) * 64 + kx;
    const char* pb = lds + ABYT + (size_t)(wc * 64 + (lane & 15)) * 64 + kx;

    f32x4 acc[8][4] = {};

#define RDA(m) (*(const bf16x8*)(pa + bo + (m) * 1024))
#define RDB(n) (*(const bf16x8*)(pb + bo + (n) * 1024))
#define MF4(AF, m)                                                            \
    acc[m][0] = MFMA(AF, b0, acc[m][0]);                                      \
    acc[m][1] = MFMA(AF, b1, acc[m][1]);                                      \
    acc[m][2] = MFMA(AF, b2, acc[m][2]);                                      \
    acc[m][3] = MFMA(AF, b3, acc[m][3]);

    // One slab: reads rotated through the MFMA cluster (3-deep af rotation),
    // single counted vmcnt + single barrier at the end.
#define SLAB(t, DO_STAGE, VMSTMT)                                             \
    {                                                                         \
        const int bo = ((t) & 3) * SLOTB;                                     \
        bf16x8 b0 = RDB(0);                                                   \
        bf16x8 a0 = RDA(0), a1 = RDA(1), a2 = RDA(2);                         \
        bf16x8 b1 = RDB(1), b2 = RDB(2), b3 = RDB(3);                         \
        if (DO_STAGE) STAGE((t) + 3);                                         \
        __builtin_amdgcn_s_setprio(1);                                        \
        MF4(a0, 0)  a0 = RDA(3);                                              \
        MF4(a1, 1)  a1 = RDA(4);                                              \
        MF4(a2, 2)  a2 = RDA(5);                                              \
        MF4(a0, 3)  a0 = RDA(6);                                              \
        MF4(a1, 4)  a1 = RDA(7);                                              \
        MF4(a2, 5)                                                            \
        MF4(a0, 6)                                                            \
        MF4(a1, 7)                                                            \
        __builtin_amdgcn_s_setprio(0);                                        \
        VMSTMT;                                                               \
        BAR();                                                                \
    }

    const int NT = K >> 5;                   // 128 slabs of 32 k

    // prologue: slabs 0,1,2 in flight; confirm slab 0
    STAGE(0); STAGE(1); STAGE(2);
    VMCNT(8);
    BAR();

    for (int t = 0; t < NT - 3; ++t)
        SLAB(t, true, VMCNT(8));             // confirm t+1; t+2,t+3 stay in flight
    SLAB(NT - 3, false, VMCNT(4));
    SLAB(NT - 2, false, VMCNT(0));
    SLAB(NT - 1, false, (void)0);

    // ---- epilogue: C/D layout row=(lane>>4)*4+i, col=lane&15 ----
    const int r0 = bm * BM + wr * 128 + ((lane >> 4) << 2);
    const int c0 = bn * BN + wc * 64 + (lane & 15);
    float bv[4];
#pragma unroll
    for (int n = 0; n < 4; ++n) bv[n] = bias[c0 + n * 16];
#pragma unroll
    for (int m = 0; m < 8; ++m)
#pragma unroll
        for (int n = 0; n < 4; ++n)
#pragma unroll
            for (int i = 0; i < 4; ++i)
                C[(size_t)(r0 + m * 16 + i) * N + (c0 + n * 16)] = acc[m][n][i] + bv[n];
}

extern "C" void kernel_launch(void* const* d_in, const int* in_sizes, int n_in,
                              void* d_out, int out_size, void* d_ws, size_t ws_size,
                              hipStream_t stream) {
    const float* x    = (const float*)d_in[0];   // [B,S,K] f32
    const float* w    = (const float*)d_in[1];   // [N,K]   f32
    const float* bias = (const float*)d_in[2];   // [N]     f32
    const float* ss   = (const float*)d_in[3];   // [K/128, N] f32
    float* out        = (float*)d_out;           // [B,S,N] f32

    const int N = in_sizes[2];            // 4096
    const int K = in_sizes[1] / N;        // 4096
    const int M = in_sizes[0] / K;        // 8192

    u16* xb = (u16*)d_ws;                        // [M][K] bf16
    u16* wb = xb + (size_t)M * K;                // [N][K] bf16

    int n8x = (M * K) >> 3;
    cvt_x_bf16<<<(n8x + 255) / 256, 256, 0, stream>>>(x, xb, n8x);

    int n8w = (N * K) >> 3;
    dequant_w_bf16<<<(n8w + 255) / 256, 256, 0, stream>>>(w, ss, wb, N, K);

    (void)hipFuncSetAttribute((const void*)gemm_bf16_bt_256,
                              hipFuncAttributeMaxDynamicSharedMemorySize, LDSB);
    dim3 grid((M / BM) * (N / BN));              // 32*16 = 512, %8 == 0
    gemm_bf16_bt_256<<<grid, 512, LDSB, stream>>>(xb, wb, bias, out, M, N, K);
}